// Round 7
// baseline (435.917 us; speedup 1.0000x reference)
//
#include <hip/hip_runtime.h>
#include <hip/hip_bf16.h>

#define SS 2048
#define BB 16
#define DD 512

typedef __attribute__((ext_vector_type(4))) float f32x4;
typedef __attribute__((ext_vector_type(16))) float f32x16;
typedef __attribute__((ext_vector_type(8))) short bf16x8;
typedef __attribute__((ext_vector_type(4))) unsigned short us4;
typedef unsigned short us;

#define MFMA16(a,b,c) __builtin_amdgcn_mfma_f32_16x16x32_bf16((a),(b),(c),0,0,0)
#define MFMA32(a,b,c) __builtin_amdgcn_mfma_f32_32x32x16_bf16((a),(b),(c),0,0,0)
#define BAR() __builtin_amdgcn_s_barrier()
#define WAITV(n) asm volatile("s_waitcnt vmcnt(" #n ")" ::: "memory")
#define WAITL()  asm volatile("s_waitcnt lgkmcnt(0)" ::: "memory")
#define ADV(s) s = ((s) == 2 ? 0 : (s) + 1)

__device__ __forceinline__ unsigned short f2b(float f) {
    union { float f; unsigned u; } v; v.f = f;
    unsigned r = v.u + 0x7FFFu + ((v.u >> 16) & 1u);
    return (unsigned short)(r >> 16);
}

// 256B-row LDS tile, 4-bit XOR swizzle (16-slot spread)
__device__ __forceinline__ bf16x8 ldfrag8(const us* base, int row, int kelem) {
    int off = (row << 8) + (kelem << 1);
    off ^= (row & 15) << 4;
    return *(const bf16x8*)((const char*)base + off);
}
// 128B-row (k_gemm)
__device__ __forceinline__ bf16x8 ldfrag(const us* base, int row, int kelem, int rowshift) {
    int off = (row << rowshift) + (kelem << 1);
    off ^= (row & 7) << 4;
    return *(const bf16x8*)((const char*)base + off);
}

__device__ __forceinline__ void gl16(const void* g, void* l) {
    __builtin_amdgcn_global_load_lds(
        (const __attribute__((address_space(1))) unsigned*)g,
        (__attribute__((address_space(3))) unsigned*)l, 16, 0, 0);
}

// ---------------------------------------------------------------------------
// Prep: seq [S][B][D] fp32 -> Xb [B][S][D] bf16 and Xbt [B][D][S] bf16.
// ---------------------------------------------------------------------------
__global__ __launch_bounds__(256) void k_prep_x(const float* __restrict__ seq,
        us* __restrict__ Xb, us* __restrict__ Xbt) {
    __shared__ __align__(16) char L[64 * 128];
    const int tid = threadIdx.x;
    const int d0 = blockIdx.x * 64, s0 = blockIdx.y * 64, b = blockIdx.z;
    {
        int r = tid >> 2, seg = (tid & 3) * 16;
        const float* src = seq + (size_t)(s0 + r) * (BB * DD) + (size_t)b * DD + d0 + seg;
        __align__(16) us vals[16];
        #pragma unroll
        for (int q = 0; q < 4; ++q) {
            f32x4 v = *(const f32x4*)(src + q * 4);
            vals[q*4+0] = f2b(v.x); vals[q*4+1] = f2b(v.y);
            vals[q*4+2] = f2b(v.z); vals[q*4+3] = f2b(v.w);
        }
        us* xo = Xb + ((size_t)b * SS + s0 + r) * DD + d0 + seg;
        *(bf16x8*)xo       = *(bf16x8*)&vals[0];
        *(bf16x8*)(xo + 8) = *(bf16x8*)&vals[8];
        #pragma unroll
        for (int j = 0; j < 16; ++j) {
            int d = seg + j;
            int addr = (d * 128 + r * 2) ^ ((d & 7) << 4);
            *(us*)(L + addr) = vals[j];
        }
    }
    __syncthreads();
    {
        int d = tid >> 2, sseg = (tid & 3) * 16;
        int c = (d & 7) << 4;
        int base = d * 128 + sseg * 2;
        bf16x8 h0 = *(bf16x8*)(L + (base ^ c));
        bf16x8 h1 = *(bf16x8*)(L + ((base + 16) ^ c));
        us* o = Xbt + ((size_t)b * DD + d0 + d) * SS + s0 + sseg;
        *(bf16x8*)o       = h0;
        *(bf16x8*)(o + 8) = h1;
    }
}

// ---------------------------------------------------------------------------
// Gt[p][i] = (1/sqrt(D)) * sum_a Wv[a,i] * Wq[a,p]
// ---------------------------------------------------------------------------
__global__ __launch_bounds__(256) void k_prepG(const float* __restrict__ Wv,
        const float* __restrict__ Wq, us* __restrict__ Gt) {
    __shared__ float Sq[32][64], Sv[32][64];
    const int tid = threadIdx.x;
    const int p0 = blockIdx.x * 64, i0 = blockIdx.y * 64;
    const int tp = tid & 15, ti = tid >> 4;
    float acc[4][4] = {};
    for (int a0 = 0; a0 < DD; a0 += 32) {
        #pragma unroll
        for (int j = 0; j < 2; ++j) {
            int slot = tid + j * 256;
            int row = slot >> 4, c4 = (slot & 15) * 4;
            *(f32x4*)&Sq[row][c4] = *(const f32x4*)(Wq + (size_t)(a0 + row) * DD + p0 + c4);
            *(f32x4*)&Sv[row][c4] = *(const f32x4*)(Wv + (size_t)(a0 + row) * DD + i0 + c4);
        }
        __syncthreads();
        for (int a = 0; a < 32; ++a) {
            f32x4 q = *(f32x4*)&Sq[a][tp * 4];
            f32x4 v = *(f32x4*)&Sv[a][ti * 4];
            #pragma unroll
            for (int x = 0; x < 4; ++x)
                #pragma unroll
                for (int y = 0; y < 4; ++y)
                    acc[x][y] += q[x] * v[y];
        }
        __syncthreads();
    }
    const float sc = 0.044194173824159216f;
    #pragma unroll
    for (int x = 0; x < 4; ++x)
        #pragma unroll
        for (int y = 0; y < 4; ++y)
            Gt[(size_t)(p0 + tp * 4 + x) * DD + i0 + ti * 4 + y] = f2b(acc[x][y] * sc);
}

// u[p] = (1/sqrt(D)) * sum_a bv[a] * Wq[a,p]
__global__ __launch_bounds__(512) void k_prepU(const float* __restrict__ Wq,
        const float* __restrict__ bv, float* __restrict__ u) {
    int p = threadIdx.x;
    float s = 0.f;
    for (int a0 = 0; a0 < DD; a0 += 8) {
        #pragma unroll
        for (int j = 0; j < 8; ++j)
            s += bv[a0 + j] * Wq[(size_t)(a0 + j) * DD + p];
    }
    u[p] = s * 0.044194173824159216f;
}

__global__ void k_prepW(const float* __restrict__ Wk, us* __restrict__ Wkb) {
    int i = (blockIdx.x * 256 + threadIdx.x) * 4;
    f32x4 v = *(const f32x4*)(Wk + i);
    us4 o; o.x = f2b(v.x); o.y = f2b(v.y); o.z = f2b(v.z); o.w = f2b(v.w);
    *(us4*)(Wkb + i) = o;
}

// ---------------------------------------------------------------------------
// bf16 GEMM: C[row,n] = sum_k A[row,k]*Bm[n,k] + bias[n]
// ---------------------------------------------------------------------------
template<int OUTMODE>
__global__ __launch_bounds__(256, 2) void k_gemm(
        const us* __restrict__ A, const us* __restrict__ Bm,
        const float* __restrict__ bias, void* __restrict__ outp) {
    __shared__ __align__(16) us As[2][128 * 64];
    __shared__ __align__(16) us Bs[2][128 * 64];
    const int tid = threadIdx.x;
    const int lane = tid & 63;
    const int w = tid >> 6;
    const int wr = w >> 1, wc = w & 1;
    const int l15 = lane & 15, lg = lane >> 4;
    const int b = blockIdx.x >> 4;
    const int s0 = (blockIdx.x & 15) * 128;
    const int n0 = blockIdx.y * 128;
    const char* abase = (const char*)(A + ((size_t)b * SS + s0) * DD);
    const char* bbase = (const char*)Bm + (size_t)n0 * 1024;

    f32x4 acc[4][4];
    #pragma unroll
    for (int m = 0; m < 4; ++m)
        #pragma unroll
        for (int n = 0; n < 4; ++n) acc[m][n] = (f32x4)(0.0f);

    auto stage = [&](int db, int p) {
        #pragma unroll
        for (int j = 0; j < 4; ++j) {
            int x = (tid + j * 256) * 16;
            int gx = x ^ (((x >> 7) & 7) << 4);
            int row = gx >> 7, col = gx & 127;
            gl16(abase + (size_t)row * 1024 + p * 128 + col, (char*)As[db] + x);
            gl16(bbase + (size_t)row * 1024 + p * 128 + col, (char*)Bs[db] + x);
        }
    };

    stage(0, 0);
    for (int p = 0; p < 8; ++p) {
        if (p < 7) { stage((p + 1) & 1, p + 1); WAITV(8); }
        else       { WAITV(0); }
        BAR();
        const us* Ac = As[p & 1]; const us* Bc = Bs[p & 1];
        __builtin_amdgcn_s_setprio(1);
        #pragma unroll
        for (int kk = 0; kk < 2; ++kk) {
            bf16x8 af[4], bfr[4];
            #pragma unroll
            for (int m = 0; m < 4; ++m) af[m]  = ldfrag(Ac, 64 * wr + 16 * m + l15, kk * 32 + 8 * lg, 7);
            #pragma unroll
            for (int n = 0; n < 4; ++n) bfr[n] = ldfrag(Bc, 64 * wc + 16 * n + l15, kk * 32 + 8 * lg, 7);
            #pragma unroll
            for (int m = 0; m < 4; ++m)
                #pragma unroll
                for (int n = 0; n < 4; ++n)
                    acc[m][n] = MFMA16(af[m], bfr[n], acc[m][n]);
        }
        __builtin_amdgcn_s_setprio(0);
        BAR();
    }

    #pragma unroll
    for (int m = 0; m < 4; ++m) {
        #pragma unroll
        for (int n = 0; n < 4; ++n) {
            int col = n0 + 64 * wc + 16 * n + l15;
            float bia = bias[col];
            #pragma unroll
            for (int r = 0; r < 4; ++r) {
                int row = s0 + 64 * wr + 16 * m + 4 * lg + r;
                float v = acc[m][n][r] + bia;
                if (OUTMODE == 0)
                    ((us*)outp)[((size_t)b * SS + row) * DD + col] = f2b(v);
                else
                    ((float*)outp)[((size_t)row * BB + b) * DD + col] = v;
            }
        }
    }
}

// ---------------------------------------------------------------------------
// Flash attention v6: 32x32x16 MFMA, folded operands, static-max softmax.
//   QB=64 (512 blocks), 8 waves = 2 rg (32 rows) x 4 cg.
//   af: Vt A-fragments k<384 in regs (96 VGPR); k>=384 in persistent VtL LDS.
//   Per step (KV=128): 4 QK chunks [128t][128k] + 4 PV chunks [128e][128t],
//   32KB each, ring-3, depth-2, WAITV(8).  B redundancy 2 (vs 4 at 16x16).
//   Row-sums via ones-B MFMA into lsumv (same C row layout as accv ->
//   epilogue divide needs no cross-lane exchange).
// ---------------------------------------------------------------------------
__global__ __launch_bounds__(512, 2) void k_attn(
        const us* __restrict__ Vtb, const us* __restrict__ Xb,
        const us* __restrict__ Xbt, us* __restrict__ Ob) {
    __shared__ __align__(16) us BUFS[3][16384];  // 3 x 32KB ring
    __shared__ __align__(16) us VtL[64 * 128];   // Vt k 384..511, persistent
    __shared__ __align__(16) us Pb[64 * 128];    // P [64 r][128 t]

    const int tid = threadIdx.x;
    const int lane = tid & 63;
    const int w = tid >> 6;
    const int rg = w & 1;          // rows 32*rg .. +31
    const int cg = w >> 1;         // col group 0..3
    const int l31 = lane & 31, lh = lane >> 5;

    const int wg = blockIdx.x;
    const int b  = wg & 15;        // XCD x owns batches {x, x+8}
    const int s0 = (wg >> 4) * 64;

    const char* vbase  = (const char*)(Vtb + ((size_t)b * SS + s0) * DD);
    const char* xabase = (const char*)(Xb  + (size_t)b * SS * DD);
    const char* xtbase = (const char*)(Xbt + (size_t)b * DD * SS);

    // chunk c (8/step): i=c&7: i<4 -> X k-quarter i rows t0..t0+127;
    //                   i>=4 -> XT e-window (i-4) cols t0..t0+127
    auto issue = [&](int cflat, us* dst0) {
        int c = cflat & 127;
        int i = c & 7, t0 = (c >> 3) << 7;
        char* dst = (char*)dst0;
        if (i < 4) {
            #pragma unroll
            for (int j = 0; j < 4; ++j) {
                int x = tid * 16 + j * 8192;
                int gx = x ^ (((x >> 8) & 15) << 4);
                int row = gx >> 8, col = gx & 255;
                gl16(xabase + (size_t)(t0 + row) * 1024 + i * 256 + col, dst + x);
            }
        } else {
            #pragma unroll
            for (int j = 0; j < 4; ++j) {
                int x = tid * 16 + j * 8192;
                int gx = x ^ (((x >> 8) & 15) << 4);
                int row = gx >> 8, col = gx & 255;
                gl16(xtbase + (size_t)((i - 4) * 128 + row) * (SS * 2)
                            + (size_t)t0 * 2 + col, dst + x);
            }
        }
    };

    // ---- prologue: Vt tile [64][512] -> 4 sub-chunks [64][128] (16KB) ----
    #pragma unroll
    for (int p = 0; p < 4; ++p) {
        char* dst = (p < 3) ? (char*)BUFS[p] : (char*)VtL;
        #pragma unroll
        for (int j = 0; j < 2; ++j) {
            int x = tid * 16 + j * 8192;
            int gx = x ^ (((x >> 8) & 15) << 4);
            int row = gx >> 8, col = gx & 255;
            gl16(vbase + (size_t)row * 1024 + p * 256 + col, dst + x);
        }
    }
    WAITV(0); BAR();
    bf16x8 af[24];                 // k < 384: A-fragments in regs
    #pragma unroll
    for (int p = 0; p < 3; ++p)
        #pragma unroll
        for (int ks = 0; ks < 8; ++ks)
            af[8 * p + ks] = ldfrag8(BUFS[p], 32 * rg + l31, 16 * ks + 8 * lh);
    WAITL(); BAR();

    int wslot = 0, rslot = 0;
    issue(0, BUFS[wslot]); ADV(wslot);
    issue(1, BUFS[wslot]); ADV(wslot);

    const short one_bf = (short)0x3F80;
    const bf16x8 ones = {one_bf, one_bf, one_bf, one_bf,
                         one_bf, one_bf, one_bf, one_bf};

    f32x16 accv[4];
    #pragma unroll
    for (int j = 0; j < 4; ++j) accv[j] = (f32x16)(0.0f);
    f32x16 lsumv = (f32x16)(0.0f);

    for (int step = 0; step < 16; ++step) {
        const int cbase = step * 8;
        f32x16 sacc = (f32x16)(0.0f);

        // -------- QK: 4 phases (k-quarters), one 32x32 tile per wave ------
        #pragma unroll
        for (int p = 0; p < 4; ++p) {
            issue(cbase + p + 2, BUFS[wslot]); ADV(wslot);
            WAITV(8); BAR();
            const us* sl = BUFS[rslot]; ADV(rslot);
            __builtin_amdgcn_s_setprio(1);
            #pragma unroll
            for (int ks = 0; ks < 8; ++ks) {
                bf16x8 a = (p < 3) ? af[8 * p + ks]
                                   : ldfrag8(VtL, 32 * rg + l31, 16 * ks + 8 * lh);
                bf16x8 bq = ldfrag8(sl, 32 * cg + l31, 16 * ks + 8 * lh);
                sacc = MFMA32(a, bq, sacc);
            }
            __builtin_amdgcn_s_setprio(0);
            BAR();
        }

        // -------- softmax (static max): P = exp(s) -> Pb ------------------
        #pragma unroll
        for (int r = 0; r < 16; ++r)
            sacc[r] = __expf(sacc[r]);
        #pragma unroll
        for (int r = 0; r < 16; ++r) {
            int row = 32 * rg + (r & 3) + 8 * (r >> 2) + 4 * lh;
            int col = 32 * cg + l31;
            int off = ((row << 8) + (col << 1)) ^ ((row & 15) << 4);
            *(us*)((char*)Pb + off) = f2b(sacc[r]);
        }
        WAITL(); BAR();

        // pa hoist + exact row-sums via ones-B MFMA (matches accv layout)
        bf16x8 pa[8];
        #pragma unroll
        for (int ts = 0; ts < 8; ++ts)
            pa[ts] = ldfrag8(Pb, 32 * rg + l31, 16 * ts + 8 * lh);
        #pragma unroll
        for (int ts = 0; ts < 8; ++ts)
            lsumv = MFMA32(pa[ts], ones, lsumv);

        // -------- PV: 4 phases (e-windows), strided cg tiles --------------
        #pragma unroll
        for (int p = 0; p < 4; ++p) {
            issue(cbase + p + 6, BUFS[wslot]); ADV(wslot);
            WAITV(8); BAR();
            const us* sl = BUFS[rslot]; ADV(rslot);
            __builtin_amdgcn_s_setprio(1);
            #pragma unroll
            for (int ts = 0; ts < 8; ++ts) {
                bf16x8 bx = ldfrag8(sl, 32 * cg + l31, 16 * ts + 8 * lh);
                accv[p] = MFMA32(pa[ts], bx, accv[p]);
            }
            __builtin_amdgcn_s_setprio(0);
            BAR();
        }
    }

    // -------- epilogue: O' = accv / lsumv (same row layout) -> bf16 -------
    us* orow = Ob + ((size_t)b * SS + s0) * DD;
    #pragma unroll
    for (int j = 0; j < 4; ++j)
        #pragma unroll
        for (int r = 0; r < 16; ++r) {
            int row = 32 * rg + (r & 3) + 8 * (r >> 2) + 4 * lh;
            int e = 128 * j + 32 * cg + l31;
            orow[(size_t)row * DD + e] = f2b(accv[j][r] / lsumv[r]);
        }
}

extern "C" void kernel_launch(void* const* d_in, const int* in_sizes, int n_in,
                              void* d_out, int out_size, void* d_ws, size_t ws_size,
                              hipStream_t stream) {
    const float* seq = (const float*)d_in[0];
    const float* Wv  = (const float*)d_in[1];
    const float* bv  = (const float*)d_in[2];
    const float* Wq  = (const float*)d_in[3];
    // d_in[4] = bq: softmax-row-constant -> unused
    const float* Wk  = (const float*)d_in[5];
    const float* bk  = (const float*)d_in[6];

    char* ws = (char*)d_ws;
    us*    Xb  = (us*)ws;                                  // [B][S][D] bf16, 32MB
    us*    Xbt = (us*)(ws + (size_t)33554432);             // [B][D][S] bf16, 32MB
    us*    Vtb = (us*)(ws + (size_t)67108864);             // [B][S][D] bf16, 32MB (reused as O')
    us*    Gt  = (us*)(ws + (size_t)100663296);            // [D][D] bf16
    us*    Wkb = (us*)(ws + (size_t)101187584);            // [D][D] bf16
    float* u   = (float*)(ws + (size_t)101711872);         // [D] fp32

    k_prep_x<<<dim3(8, 32, 16), 256, 0, stream>>>(seq, Xb, Xbt);
    k_prepG<<<dim3(8, 8), 256, 0, stream>>>(Wv, Wq, Gt);
    k_prepU<<<1, 512, 0, stream>>>(Wq, bv, u);
    k_prepW<<<256, 256, 0, stream>>>(Wk, Wkb);

    k_gemm<0><<<dim3(256, 4), 256, 0, stream>>>(Xb, Gt, u, (void*)Vtb);   // Vt = X*G + u
    k_attn<<<512, 512, 0, stream>>>(Vtb, Xb, Xbt, Vtb);                   // O' over Vt
    k_gemm<1><<<dim3(256, 4), 256, 0, stream>>>(Vtb, Wkb, bk, d_out);     // out = O'*Wk^T + bk
}

// Round 8
// 384.472 us; speedup vs baseline: 1.1338x; 1.1338x over previous
//
#include <hip/hip_runtime.h>
#include <hip/hip_bf16.h>

#define SS 2048
#define BB 16
#define DD 512

typedef __attribute__((ext_vector_type(4))) float f32x4;
typedef __attribute__((ext_vector_type(8))) short bf16x8;
typedef __attribute__((ext_vector_type(4))) unsigned short us4;
typedef unsigned short us;

#define MFMA16(a,b,c) __builtin_amdgcn_mfma_f32_16x16x32_bf16((a),(b),(c),0,0,0)
#define BAR() __builtin_amdgcn_s_barrier()
#define WAITV(n) asm volatile("s_waitcnt vmcnt(" #n ")" ::: "memory")
#define WAITL()  asm volatile("s_waitcnt lgkmcnt(0)" ::: "memory")
#define ADV(s) s = ((s) == 2 ? 0 : (s) + 1)

__device__ __forceinline__ unsigned short f2b(float f) {
    union { float f; unsigned u; } v; v.f = f;
    unsigned r = v.u + 0x7FFFu + ((v.u >> 16) & 1u);
    return (unsigned short)(r >> 16);
}

// 256B-row LDS tile, 4-bit XOR swizzle (16-slot spread)
__device__ __forceinline__ bf16x8 ldfrag8(const us* base, int row, int kelem) {
    int off = (row << 8) + (kelem << 1);
    off ^= (row & 15) << 4;
    return *(const bf16x8*)((const char*)base + off);
}
// 128B-row (k_gemm)
__device__ __forceinline__ bf16x8 ldfrag(const us* base, int row, int kelem, int rowshift) {
    int off = (row << rowshift) + (kelem << 1);
    off ^= (row & 7) << 4;
    return *(const bf16x8*)((const char*)base + off);
}

__device__ __forceinline__ void gl16(const void* g, void* l) {
    __builtin_amdgcn_global_load_lds(
        (const __attribute__((address_space(1))) unsigned*)g,
        (__attribute__((address_space(3))) unsigned*)l, 16, 0, 0);
}

// ---------------------------------------------------------------------------
// Prep: seq [S][B][D] fp32 -> Xb [B][S][D] bf16 and Xbt [B][D][S] bf16.
// ---------------------------------------------------------------------------
__global__ __launch_bounds__(256) void k_prep_x(const float* __restrict__ seq,
        us* __restrict__ Xb, us* __restrict__ Xbt) {
    __shared__ __align__(16) char L[64 * 128];
    const int tid = threadIdx.x;
    const int d0 = blockIdx.x * 64, s0 = blockIdx.y * 64, b = blockIdx.z;
    {
        int r = tid >> 2, seg = (tid & 3) * 16;
        const float* src = seq + (size_t)(s0 + r) * (BB * DD) + (size_t)b * DD + d0 + seg;
        __align__(16) us vals[16];
        #pragma unroll
        for (int q = 0; q < 4; ++q) {
            f32x4 v = *(const f32x4*)(src + q * 4);
            vals[q*4+0] = f2b(v.x); vals[q*4+1] = f2b(v.y);
            vals[q*4+2] = f2b(v.z); vals[q*4+3] = f2b(v.w);
        }
        us* xo = Xb + ((size_t)b * SS + s0 + r) * DD + d0 + seg;
        *(bf16x8*)xo       = *(bf16x8*)&vals[0];
        *(bf16x8*)(xo + 8) = *(bf16x8*)&vals[8];
        #pragma unroll
        for (int j = 0; j < 16; ++j) {
            int d = seg + j;
            int addr = (d * 128 + r * 2) ^ ((d & 7) << 4);
            *(us*)(L + addr) = vals[j];
        }
    }
    __syncthreads();
    {
        int d = tid >> 2, sseg = (tid & 3) * 16;
        int c = (d & 7) << 4;
        int base = d * 128 + sseg * 2;
        bf16x8 h0 = *(bf16x8*)(L + (base ^ c));
        bf16x8 h1 = *(bf16x8*)(L + ((base + 16) ^ c));
        us* o = Xbt + ((size_t)b * DD + d0 + d) * SS + s0 + sseg;
        *(bf16x8*)o       = h0;
        *(bf16x8*)(o + 8) = h1;
    }
}

// ---------------------------------------------------------------------------
// Gt[p][i] = (1/sqrt(D)) * sum_a Wv[a,i] * Wq[a,p]
// ---------------------------------------------------------------------------
__global__ __launch_bounds__(256) void k_prepG(const float* __restrict__ Wv,
        const float* __restrict__ Wq, us* __restrict__ Gt) {
    __shared__ float Sq[32][64], Sv[32][64];
    const int tid = threadIdx.x;
    const int p0 = blockIdx.x * 64, i0 = blockIdx.y * 64;
    const int tp = tid & 15, ti = tid >> 4;
    float acc[4][4] = {};
    for (int a0 = 0; a0 < DD; a0 += 32) {
        #pragma unroll
        for (int j = 0; j < 2; ++j) {
            int slot = tid + j * 256;
            int row = slot >> 4, c4 = (slot & 15) * 4;
            *(f32x4*)&Sq[row][c4] = *(const f32x4*)(Wq + (size_t)(a0 + row) * DD + p0 + c4);
            *(f32x4*)&Sv[row][c4] = *(const f32x4*)(Wv + (size_t)(a0 + row) * DD + i0 + c4);
        }
        __syncthreads();
        for (int a = 0; a < 32; ++a) {
            f32x4 q = *(f32x4*)&Sq[a][tp * 4];
            f32x4 v = *(f32x4*)&Sv[a][ti * 4];
            #pragma unroll
            for (int x = 0; x < 4; ++x)
                #pragma unroll
                for (int y = 0; y < 4; ++y)
                    acc[x][y] += q[x] * v[y];
        }
        __syncthreads();
    }
    const float sc = 0.044194173824159216f;
    #pragma unroll
    for (int x = 0; x < 4; ++x)
        #pragma unroll
        for (int y = 0; y < 4; ++y)
            Gt[(size_t)(p0 + tp * 4 + x) * DD + i0 + ti * 4 + y] = f2b(acc[x][y] * sc);
}

// u[p] = (1/sqrt(D)) * sum_a bv[a] * Wq[a,p]
__global__ __launch_bounds__(512) void k_prepU(const float* __restrict__ Wq,
        const float* __restrict__ bv, float* __restrict__ u) {
    int p = threadIdx.x;
    float s = 0.f;
    for (int a0 = 0; a0 < DD; a0 += 8) {
        #pragma unroll
        for (int j = 0; j < 8; ++j)
            s += bv[a0 + j] * Wq[(size_t)(a0 + j) * DD + p];
    }
    u[p] = s * 0.044194173824159216f;
}

__global__ void k_prepW(const float* __restrict__ Wk, us* __restrict__ Wkb) {
    int i = (blockIdx.x * 256 + threadIdx.x) * 4;
    f32x4 v = *(const f32x4*)(Wk + i);
    us4 o; o.x = f2b(v.x); o.y = f2b(v.y); o.z = f2b(v.z); o.w = f2b(v.w);
    *(us4*)(Wkb + i) = o;
}

// ---------------------------------------------------------------------------
// bf16 GEMM: C[row,n] = sum_k A[row,k]*Bm[n,k] + bias[n]
// ---------------------------------------------------------------------------
template<int OUTMODE>
__global__ __launch_bounds__(256, 2) void k_gemm(
        const us* __restrict__ A, const us* __restrict__ Bm,
        const float* __restrict__ bias, void* __restrict__ outp) {
    __shared__ __align__(16) us As[2][128 * 64];
    __shared__ __align__(16) us Bs[2][128 * 64];
    const int tid = threadIdx.x;
    const int lane = tid & 63;
    const int w = tid >> 6;
    const int wr = w >> 1, wc = w & 1;
    const int l15 = lane & 15, lg = lane >> 4;
    const int b = blockIdx.x >> 4;
    const int s0 = (blockIdx.x & 15) * 128;
    const int n0 = blockIdx.y * 128;
    const char* abase = (const char*)(A + ((size_t)b * SS + s0) * DD);
    const char* bbase = (const char*)Bm + (size_t)n0 * 1024;

    f32x4 acc[4][4];
    #pragma unroll
    for (int m = 0; m < 4; ++m)
        #pragma unroll
        for (int n = 0; n < 4; ++n) acc[m][n] = (f32x4)(0.0f);

    auto stage = [&](int db, int p) {
        #pragma unroll
        for (int j = 0; j < 4; ++j) {
            int x = (tid + j * 256) * 16;
            int gx = x ^ (((x >> 7) & 7) << 4);
            int row = gx >> 7, col = gx & 127;
            gl16(abase + (size_t)row * 1024 + p * 128 + col, (char*)As[db] + x);
            gl16(bbase + (size_t)row * 1024 + p * 128 + col, (char*)Bs[db] + x);
        }
    };

    stage(0, 0);
    for (int p = 0; p < 8; ++p) {
        if (p < 7) { stage((p + 1) & 1, p + 1); WAITV(8); }
        else       { WAITV(0); }
        BAR();
        const us* Ac = As[p & 1]; const us* Bc = Bs[p & 1];
        __builtin_amdgcn_s_setprio(1);
        #pragma unroll
        for (int kk = 0; kk < 2; ++kk) {
            bf16x8 af[4], bfr[4];
            #pragma unroll
            for (int m = 0; m < 4; ++m) af[m]  = ldfrag(Ac, 64 * wr + 16 * m + l15, kk * 32 + 8 * lg, 7);
            #pragma unroll
            for (int n = 0; n < 4; ++n) bfr[n] = ldfrag(Bc, 64 * wc + 16 * n + l15, kk * 32 + 8 * lg, 7);
            #pragma unroll
            for (int m = 0; m < 4; ++m)
                #pragma unroll
                for (int n = 0; n < 4; ++n)
                    acc[m][n] = MFMA16(af[m], bfr[n], acc[m][n]);
        }
        __builtin_amdgcn_s_setprio(0);
        BAR();
    }

    #pragma unroll
    for (int m = 0; m < 4; ++m) {
        #pragma unroll
        for (int n = 0; n < 4; ++n) {
            int col = n0 + 64 * wc + 16 * n + l15;
            float bia = bias[col];
            #pragma unroll
            for (int r = 0; r < 4; ++r) {
                int row = s0 + 64 * wr + 16 * m + 4 * lg + r;
                float v = acc[m][n][r] + bia;
                if (OUTMODE == 0)
                    ((us*)outp)[((size_t)b * SS + row) * DD + col] = f2b(v);
                else
                    ((float*)outp)[((size_t)row * BB + b) * DD + col] = v;
            }
        }
    }
}

// ---------------------------------------------------------------------------
// Flash attention v8: 16x16 MFMA, M=32 rows/wave, folded operands.
//   QB=64 (512 blocks), 8 waves = 2 rg (32 rows) x 4 cg.
//   A (Vt): k<256 in regs af[2][8] (64 VGPR); k>=256 in persistent VtL (32KB).
//   Per step (KV=128): 4 QK chunks X[t128][k128] + 4 PV chunks XT[e128][t128],
//   32KB each, ring-3, depth-2, WAITV(8) (v5-proven staging).
//   B-frag redundancy 2 (was 4); each B-frag feeds 2 MFMAs in-reg.
//   Row-sums via ones-B MFMA (accv-matching layout, no cross-wave exchange).
// ---------------------------------------------------------------------------
__global__ __launch_bounds__(512, 2) void k_attn(
        const us* __restrict__ Vtb, const us* __restrict__ Xb,
        const us* __restrict__ Xbt, us* __restrict__ Ob) {
    __shared__ __align__(16) us BUFS[3][16384];  // 3 x 32KB ring
    __shared__ __align__(16) us VtL[2][8192];    // Vt k 256..511, [64][128] x2
    __shared__ __align__(16) us Pb[64 * 128];    // P [64 r][128 t]

    const int tid = threadIdx.x;
    const int lane = tid & 63;
    const int w = tid >> 6;
    const int rg = w & 1;          // rows 32*rg .. +31
    const int cg = w >> 1;         // col group 0..3 (t32 in QK, e32 in PV)
    const int l15 = lane & 15, lg = lane >> 4;

    const int wg = blockIdx.x;
    const int b  = wg & 15;        // XCD x owns batches {x, x+8}
    const int s0 = (wg >> 4) * 64;

    const char* vbase  = (const char*)(Vtb + ((size_t)b * SS + s0) * DD);
    const char* xabase = (const char*)(Xb  + (size_t)b * SS * DD);
    const char* xtbase = (const char*)(Xbt + (size_t)b * DD * SS);

    // chunk c (8/step): i=c&7: i<4 -> X[t0..t0+127][128i..+128];
    //                   i>=4 -> XT[128(i-4)..+128][t0..+128]
    auto issue = [&](int cflat, us* dst0) {
        int c = cflat & 127;
        int i = c & 7, t0 = (c >> 3) << 7;
        char* dst = (char*)dst0;
        if (i < 4) {
            #pragma unroll
            for (int j = 0; j < 4; ++j) {
                int x = tid * 16 + j * 8192;
                int gx = x ^ (((x >> 8) & 15) << 4);
                int row = gx >> 8, col = gx & 255;
                gl16(xabase + (size_t)(t0 + row) * 1024 + i * 256 + col, dst + x);
            }
        } else {
            #pragma unroll
            for (int j = 0; j < 4; ++j) {
                int x = tid * 16 + j * 8192;
                int gx = x ^ (((x >> 8) & 15) << 4);
                int row = gx >> 8, col = gx & 255;
                gl16(xtbase + (size_t)((i - 4) * 128 + row) * (SS * 2)
                            + (size_t)t0 * 2 + col, dst + x);
            }
        }
    };

    // ---- prologue: Vt [64][512] as 4 chunks [64][128] (16KB each) ----
    //      chunks 0,1 -> BUFS[0],BUFS[1] (af regs);  2,3 -> VtL (persistent)
    #pragma unroll
    for (int p = 0; p < 4; ++p) {
        char* dst = (p < 2) ? (char*)BUFS[p] : (char*)VtL[p - 2];
        #pragma unroll
        for (int j = 0; j < 2; ++j) {
            int x = tid * 16 + j * 8192;
            int gx = x ^ (((x >> 8) & 15) << 4);
            int row = gx >> 8, col = gx & 255;
            gl16(vbase + (size_t)row * 1024 + p * 256 + col, dst + x);
        }
    }
    WAITV(0); BAR();
    bf16x8 af[2][8];               // [rowf][kf], k = 128*(kf>>2) + 32*(kf&3)
    #pragma unroll
    for (int rf = 0; rf < 2; ++rf)
        #pragma unroll
        for (int kf = 0; kf < 8; ++kf)
            af[rf][kf] = ldfrag8(BUFS[kf >> 2], 32 * rg + 16 * rf + l15,
                                 32 * (kf & 3) + 8 * lg);
    WAITL(); BAR();

    issue(0, BUFS[0]);
    issue(1, BUFS[1]);
    int wslot = 2, rslot = 0;

    const short one_bf = (short)0x3F80;
    const bf16x8 ones = {one_bf, one_bf, one_bf, one_bf,
                         one_bf, one_bf, one_bf, one_bf};

    f32x4 accv[4][2][2];           // [e-window][rowf][ef]
    #pragma unroll
    for (int p = 0; p < 4; ++p)
        #pragma unroll
        for (int rf = 0; rf < 2; ++rf)
            #pragma unroll
            for (int ef = 0; ef < 2; ++ef) accv[p][rf][ef] = (f32x4)(0.0f);
    f32x4 lsum[2];
    lsum[0] = (f32x4)(0.0f); lsum[1] = (f32x4)(0.0f);

    for (int step = 0; step < 16; ++step) {
        const int cbase = step * 8;
        f32x4 sacc[2][2];          // [rowf][nt]
        #pragma unroll
        for (int rf = 0; rf < 2; ++rf)
            #pragma unroll
            for (int nt = 0; nt < 2; ++nt) sacc[rf][nt] = (f32x4)(0.0f);

        // -------- QK: 4 phases (k-windows of 128) --------
        #pragma unroll
        for (int p = 0; p < 4; ++p) {
            issue(cbase + p + 2, BUFS[wslot]); ADV(wslot);
            WAITV(8); BAR();
            const us* sl = BUFS[rslot]; ADV(rslot);
            __builtin_amdgcn_s_setprio(1);
            #pragma unroll
            for (int kk = 0; kk < 4; ++kk) {
                bf16x8 a0, a1;
                if (p < 2) { a0 = af[0][4 * p + kk]; a1 = af[1][4 * p + kk]; }
                else {
                    a0 = ldfrag8(VtL[p - 2], 32 * rg + l15,      32 * kk + 8 * lg);
                    a1 = ldfrag8(VtL[p - 2], 32 * rg + 16 + l15, 32 * kk + 8 * lg);
                }
                #pragma unroll
                for (int nt = 0; nt < 2; ++nt) {
                    bf16x8 bq = ldfrag8(sl, 32 * cg + 16 * nt + l15, 32 * kk + 8 * lg);
                    sacc[0][nt] = MFMA16(a0, bq, sacc[0][nt]);
                    sacc[1][nt] = MFMA16(a1, bq, sacc[1][nt]);
                }
            }
            __builtin_amdgcn_s_setprio(0);
            BAR();
        }

        // -------- softmax (static max): P = exp(s) -> Pb --------
        #pragma unroll
        for (int rf = 0; rf < 2; ++rf)
            #pragma unroll
            for (int nt = 0; nt < 2; ++nt)
                #pragma unroll
                for (int ri = 0; ri < 4; ++ri)
                    sacc[rf][nt][ri] = __expf(sacc[rf][nt][ri]);
        #pragma unroll
        for (int rf = 0; rf < 2; ++rf)
            #pragma unroll
            for (int nt = 0; nt < 2; ++nt)
                #pragma unroll
                for (int ri = 0; ri < 4; ++ri) {
                    int row = 32 * rg + 16 * rf + 4 * lg + ri;
                    int col = 32 * cg + 16 * nt + l15;
                    int off = ((row << 8) + (col << 1)) ^ ((row & 15) << 4);
                    *(us*)((char*)Pb + off) = f2b(sacc[rf][nt][ri]);
                }
        WAITL(); BAR();

        // pa hoist + exact row-sums via ones-B MFMA (accv-matching layout)
        bf16x8 pa[2][4];
        #pragma unroll
        for (int rf = 0; rf < 2; ++rf)
            #pragma unroll
            for (int ts = 0; ts < 4; ++ts)
                pa[rf][ts] = ldfrag8(Pb, 32 * rg + 16 * rf + l15, 32 * ts + 8 * lg);
        #pragma unroll
        for (int rf = 0; rf < 2; ++rf)
            #pragma unroll
            for (int ts = 0; ts < 4; ++ts)
                lsum[rf] = MFMA16(pa[rf][ts], ones, lsum[rf]);

        // -------- PV: 4 phases (e-windows of 128) --------
        #pragma unroll
        for (int p = 0; p < 4; ++p) {
            issue(cbase + p + 6, BUFS[wslot]); ADV(wslot);
            WAITV(8); BAR();
            const us* sl = BUFS[rslot]; ADV(rslot);
            __builtin_amdgcn_s_setprio(1);
            #pragma unroll
            for (int kk = 0; kk < 4; ++kk) {
                #pragma unroll
                for (int ef = 0; ef < 2; ++ef) {
                    bf16x8 bx = ldfrag8(sl, 32 * cg + 16 * ef + l15, 32 * kk + 8 * lg);
                    accv[p][0][ef] = MFMA16(pa[0][kk], bx, accv[p][0][ef]);
                    accv[p][1][ef] = MFMA16(pa[1][kk], bx, accv[p][1][ef]);
                }
            }
            __builtin_amdgcn_s_setprio(0);
            BAR();
        }
    }

    // -------- epilogue: O' = accv / lsum (same row layout) -> bf16 --------
    us* orow = Ob + ((size_t)b * SS + s0) * DD;
    #pragma unroll
    for (int p = 0; p < 4; ++p)
        #pragma unroll
        for (int rf = 0; rf < 2; ++rf)
            #pragma unroll
            for (int ef = 0; ef < 2; ++ef)
                #pragma unroll
                for (int ri = 0; ri < 4; ++ri) {
                    int row = 32 * rg + 16 * rf + 4 * lg + ri;
                    int e = 128 * p + 32 * cg + 16 * ef + l15;
                    orow[(size_t)row * DD + e] = f2b(accv[p][rf][ef][ri] / lsum[rf][ri]);
                }
}

extern "C" void kernel_launch(void* const* d_in, const int* in_sizes, int n_in,
                              void* d_out, int out_size, void* d_ws, size_t ws_size,
                              hipStream_t stream) {
    const float* seq = (const float*)d_in[0];
    const float* Wv  = (const float*)d_in[1];
    const float* bv  = (const float*)d_in[2];
    const float* Wq  = (const float*)d_in[3];
    // d_in[4] = bq: softmax-row-constant -> unused
    const float* Wk  = (const float*)d_in[5];
    const float* bk  = (const float*)d_in[6];

    char* ws = (char*)d_ws;
    us*    Xb  = (us*)ws;                                  // [B][S][D] bf16, 32MB
    us*    Xbt = (us*)(ws + (size_t)33554432);             // [B][D][S] bf16, 32MB
    us*    Vtb = (us*)(ws + (size_t)67108864);             // [B][S][D] bf16, 32MB (reused as O')
    us*    Gt  = (us*)(ws + (size_t)100663296);            // [D][D] bf16
    us*    Wkb = (us*)(ws + (size_t)101187584);            // [D][D] bf16
    float* u   = (float*)(ws + (size_t)101711872);         // [D] fp32

    k_prep_x<<<dim3(8, 32, 16), 256, 0, stream>>>(seq, Xb, Xbt);
    k_prepG<<<dim3(8, 8), 256, 0, stream>>>(Wv, Wq, Gt);
    k_prepU<<<1, 512, 0, stream>>>(Wq, bv, u);
    k_prepW<<<256, 256, 0, stream>>>(Wk, Wkb);

    k_gemm<0><<<dim3(256, 4), 256, 0, stream>>>(Xb, Gt, u, (void*)Vtb);   // Vt = X*G + u
    k_attn<<<512, 512, 0, stream>>>(Vtb, Xb, Xbt, Vtb);                   // O' over Vt
    k_gemm<1><<<dim3(256, 4), 256, 0, stream>>>(Vtb, Wkb, bk, d_out);     // out = O'*Wk^T + bk
}